// Round 7
// baseline (248.731 us; speedup 1.0000x reference)
//
#include <hip/hip_runtime.h>

// Volume rendering composite (cumprod along chunk-row axis, per-column).
// s[b,p] = density*delta >= 0; T = exp(-prefix(s)); monotone prefix =>
// exp(-S)==0 exactly in fp32 for S>110, so late contributions are exactly 0.
//
// 2-kernel structure:
//   K1 seg_sum:   float4 loads (16B/lane); per-segment (8-row) column sums
//                 -> wsA, superblock (64-row) sums -> wsBS; zeroes the
//                 per-chunk completion counters (NO hipMemsetAsync: the
//                 rocclr fill kernel measured 57us/dispatch in-graph).
//   K2 composite: block (sb,c) rebuilds its prefix base from coalesced
//                 L2-resident superblock sums (fixed order) + intra-block
//                 segment prefix in LDS; live waves composite with __expf;
//                 LDS tree-reduce; ONE plain 512-float partial store; then
//                 per-chunk counter atomicAdd — the LAST block of each chunk
//                 does the fixed-order reduction of 128 partials -> d_out.
//                 No memsets, 1024 atomics total, deterministic.

#define P 128
#define FARD 1.0e10f
#define SKIP_S 110.0f
#define SB 8           // segments (waves) per block
#define LROWS 8        // rows per segment; superblock = 64 rows

__global__ __launch_bounds__(512) void seg_sum_kernel(
    const float4* __restrict__ d4,
    const float4* __restrict__ z4p,
    float4* __restrict__ wsA4,   // [c][g][32] per-segment sums (float4 view)
    float4* __restrict__ wsBS4,  // [c][sb][32] superblock sums
    int* __restrict__ cnt,       // [n_chunks] completion counters
    int G, int nsb, int chunk)
{
    __shared__ float4 ls[SB][32];
    const int tid = threadIdx.x;
    const int w = tid >> 6, t = tid & 63;        // wave -> segment
    const int h = t >> 5, j = t & 31;            // half-wave row parity, col/4
    const int sb = blockIdx.x, c = blockIdx.y;
    const int g = sb * SB + w;
    const long long row0 = (long long)c * chunk + (long long)g * LROWS;

    float s0 = 0.f, s1 = 0.f, s2 = 0.f, s3 = 0.f;
    #pragma unroll
    for (int i = 0; i < LROWS / 2; ++i) {
        const long long row = row0 + 2 * i + h;  // h=0: even rows, h=1: odd
        float4 d = d4[row * 32 + j];
        float4 z = z4p[row * 32 + j];
        float zn = __shfl_down(z.x, 1);          // next 4-col group's z0
        s0 += d.x * (z.y - z.x);
        s1 += d.y * (z.z - z.y);
        s2 += d.z * (z.w - z.z);
        s3 += d.w * ((j == 31) ? FARD : (zn - z.w));
    }
    // combine row parities: lane t += lane t+32
    s0 += __shfl_down(s0, 32); s1 += __shfl_down(s1, 32);
    s2 += __shfl_down(s2, 32); s3 += __shfl_down(s3, 32);
    if (h == 0) {
        float4 o = make_float4(s0, s1, s2, s3);
        wsA4[((long long)c * G + g) * 32 + j] = o;
        ls[w][j] = o;
    }
    __syncthreads();
    if (w == 0 && h == 0) {
        float4 b = ls[0][j];
        #pragma unroll
        for (int k = 1; k < SB; ++k) {
            float4 v = ls[k][j];
            b.x += v.x; b.y += v.y; b.z += v.z; b.w += v.w;
        }
        wsBS4[((long long)c * nsb + sb) * 32 + j] = b;
    }
    if (sb == 0 && tid == 0) cnt[c] = 0;         // visible to K2 at dispatch
}

__global__ __launch_bounds__(512) void composite_kernel(
    const float* __restrict__ density,
    const float* __restrict__ feature,
    const float* __restrict__ depth,
    const float* __restrict__ wsA,
    const float* __restrict__ wsBS,
    float* __restrict__ wsB,    // [c][sb][512] partials
    int* __restrict__ cnt,
    float* __restrict__ out,
    int G, int nsb, int chunk, int n_chunks)
{
    __shared__ float part[4][P];
    __shared__ float base[P];
    __shared__ float seg[SB][P];
    __shared__ float red[SB][512];
    __shared__ int lastFlag;
    const int tid = threadIdx.x;
    const int w = tid >> 6, t = tid & 63;
    const int sb = blockIdx.x, c = blockIdx.y;

    // base[p] = sum_{sb'<sb} wsBS[c][sb'][p], fixed-order 4-way split.
    {
        const int p = tid & (P - 1), j = tid >> 7;        // j = 0..3
        float s = 0.f;
        for (int sbp = j; sbp < sb; sbp += 4)
            s += wsBS[((long long)c * nsb + sbp) * P + p];
        part[j][p] = s;
    }
    // Own 8 segment sums -> LDS (2 coalesced loads per thread).
    {
        int idx = tid;
        int w2 = idx >> 7, p2 = idx & (P - 1);
        seg[w2][p2] = wsA[((long long)c * G + sb * SB + w2) * P + p2];
        idx += 512; w2 = idx >> 7; p2 = idx & (P - 1);
        seg[w2][p2] = wsA[((long long)c * G + sb * SB + w2) * P + p2];
    }
    __syncthreads();
    if (tid < P)
        base[tid] = (part[0][tid] + part[1][tid]) + (part[2][tid] + part[3][tid]);
    __syncthreads();

    const int p0 = 2 * t;
    float Sx = base[p0], Sy = base[p0 + 1];
    for (int k = 0; k < w; ++k) { Sx += seg[k][p0]; Sy += seg[k][p0 + 1]; }

    float fa0 = 0.f, fa1 = 0.f, fa2 = 0.f;
    float fb0 = 0.f, fb1 = 0.f, fb2 = 0.f;
    float da = 0.f, db = 0.f;

    const bool dead = __all((Sx > SKIP_S) && (Sy > SKIP_S));
    if (!dead) {
        const int g = sb * SB + w;
        const long long row0 = (long long)c * chunk + (long long)g * LROWS;
        const float2* __restrict__ d2 = (const float2*)density;
        const float2* __restrict__ z2 = (const float2*)depth;
        const float2* __restrict__ f2 = (const float2*)feature;
        float tx = __expf(-Sx), ty = __expf(-Sy);  // T at segment start
        #pragma unroll
        for (int r = 0; r < LROWS; ++r) {
            const long long hh = (row0 + r) * (P / 2) + t;
            float2 d = d2[hh];
            float2 z = z2[hh];
            float zn = __shfl_down(z.x, 1);
            float sx = d.x * (z.y - z.x);
            float sy = d.y * ((t == 63) ? FARD : (zn - z.y));
            float ex = __expf(-sx), ey = __expf(-sy);
            float tnx = tx * ex, tny = ty * ey;   // running cumprod, as ref
            float wx = tx - tnx;                  // T_i * (1 - temp_i)
            float wy = ty - tny;
            tx = tnx; ty = tny;
            const long long fi = 3 * hh;
            float2 f01 = f2[fi], f23 = f2[fi + 1], f45 = f2[fi + 2];
            fa0 += wx * f01.x; fa1 += wx * f01.y; fa2 += wx * f23.x;
            fb0 += wy * f23.y; fb1 += wy * f45.x; fb2 += wy * f45.y;
            da  += wx * z.x;   db  += wy * z.y;
        }
    }

    // Per-wave partials -> LDS. Layout per wave: [p*3+comp | 384+p].
    float* rw = red[w];
    rw[p0 * 3 + 0] = fa0; rw[p0 * 3 + 1] = fa1; rw[p0 * 3 + 2] = fa2;
    rw[p0 * 3 + 3] = fb0; rw[p0 * 3 + 4] = fb1; rw[p0 * 3 + 5] = fb2;
    rw[384 + p0] = da;    rw[384 + p0 + 1] = db;
    __syncthreads();

    float s = 0.f;
    #pragma unroll
    for (int k = 0; k < SB; ++k) s += red[k][tid];
    wsB[((long long)c * nsb + sb) * 512 + tid] = s;

    // Completion counting; last block of chunk c reduces its 128 partials.
    __threadfence();
    if (tid == 0) lastFlag = (atomicAdd(&cnt[c], 1) == nsb - 1);
    __syncthreads();
    if (lastFlag) {
        __threadfence();                          // acquire remote partials
        float r = 0.f;
        #pragma unroll 4
        for (int sbp = 0; sbp < nsb; ++sbp)
            r += wsB[((long long)c * nsb + sbp) * 512 + tid];
        if (tid < 384) out[(long long)c * 384 + tid] = r;            // feat
        else out[(long long)n_chunks * 384 + (long long)c * P + (tid - 384)] = r;
    }
}

extern "C" void kernel_launch(void* const* d_in, const int* in_sizes, int n_in,
                              void* d_out, int out_size, void* d_ws, size_t ws_size,
                              hipStream_t stream)
{
    const float* density = (const float*)d_in[0];
    const float* feature = (const float*)d_in[1];
    const float* depth   = (const float*)d_in[2];
    float* out = (float*)d_out;

    const int B = in_sizes[0] / P;        // 65536
    const int chunk = 8192;               // matches setup_inputs() chunk_size
    const int n_chunks = B / chunk;       // 8
    const int nsb = chunk / (SB * LROWS); // 128 superblocks per chunk
    const int G = nsb * SB;               // 1024 segments per chunk

    float* wsA  = (float*)d_ws;                          // 4 MB
    float* wsBS = wsA + (size_t)n_chunks * G * P;        // 0.5 MB
    float* wsB  = wsBS + (size_t)n_chunks * nsb * P;     // 2 MB
    int*   cnt  = (int*)(wsB + (size_t)n_chunks * nsb * 512);

    dim3 grid(nsb, n_chunks);
    seg_sum_kernel<<<grid, 512, 0, stream>>>(
        (const float4*)density, (const float4*)depth,
        (float4*)wsA, (float4*)wsBS, cnt, G, nsb, chunk);
    composite_kernel<<<grid, 512, 0, stream>>>(
        density, feature, depth, wsA, wsBS, wsB, cnt, out,
        G, nsb, chunk, n_chunks);
}

// Round 8
// 41.762 us; speedup vs baseline: 5.9559x; 5.9559x over previous
//
#include <hip/hip_runtime.h>

// Volume rendering composite (cumprod along chunk-row axis, per-column).
// s[b,p] = density*delta >= 0; T = exp(-prefix(s)); monotone prefix =>
// exp(-S)==0 exactly in fp32 for S>110, so late contributions are exactly 0.
//
// 3-kernel structure. Round-7 lesson: fusing the final reduce into K2 via
// per-chunk counter + __threadfence() cost ~260us — device-scope fences
// from 1024 blocks serialize L2 writebacks across the 8 non-coherent XCD
// L2s. Separate 3us reduce dispatch is far cheaper than cross-XCD fencing.
//   K1 seg_sum:   float4 loads (16B/lane, 2 rows/wave-iter); per-segment
//                 (8-row) column sums -> wsA, superblock sums -> wsBS.
//   K2 composite: block (sb,c) rebuilds prefix base from coalesced
//                 L2-resident superblock sums (fixed order) + intra-block
//                 segment prefix in LDS; live waves composite with __expf;
//                 LDS tree-reduce; ONE plain 512-float partial store.
//                 Dead blocks store zero partials (no memset needed).
//   K3 reduce:    fixed-order sum over 128 partials -> d_out.

#define P 128
#define FARD 1.0e10f
#define SKIP_S 110.0f
#define SB 8           // segments (waves) per block
#define LROWS 8        // rows per segment; superblock = 64 rows

__global__ __launch_bounds__(512) void seg_sum_kernel(
    const float4* __restrict__ d4,
    const float4* __restrict__ z4p,
    float4* __restrict__ wsA4,   // [c][g][32] per-segment sums (float4 view)
    float4* __restrict__ wsBS4,  // [c][sb][32] superblock sums
    int G, int nsb, int chunk)
{
    __shared__ float4 ls[SB][32];
    const int tid = threadIdx.x;
    const int w = tid >> 6, t = tid & 63;        // wave -> segment
    const int h = t >> 5, j = t & 31;            // half-wave row parity, col/4
    const int sb = blockIdx.x, c = blockIdx.y;
    const int g = sb * SB + w;
    const long long row0 = (long long)c * chunk + (long long)g * LROWS;

    float s0 = 0.f, s1 = 0.f, s2 = 0.f, s3 = 0.f;
    #pragma unroll
    for (int i = 0; i < LROWS / 2; ++i) {
        const long long row = row0 + 2 * i + h;  // h=0: even rows, h=1: odd
        float4 d = d4[row * 32 + j];
        float4 z = z4p[row * 32 + j];
        float zn = __shfl_down(z.x, 1);          // next 4-col group's z0
        s0 += d.x * (z.y - z.x);
        s1 += d.y * (z.z - z.y);
        s2 += d.z * (z.w - z.z);
        s3 += d.w * ((j == 31) ? FARD : (zn - z.w));
    }
    // combine row parities: lane t += lane t+32
    s0 += __shfl_down(s0, 32); s1 += __shfl_down(s1, 32);
    s2 += __shfl_down(s2, 32); s3 += __shfl_down(s3, 32);
    if (h == 0) {
        float4 o = make_float4(s0, s1, s2, s3);
        wsA4[((long long)c * G + g) * 32 + j] = o;
        ls[w][j] = o;
    }
    __syncthreads();
    if (w == 0 && h == 0) {
        float4 b = ls[0][j];
        #pragma unroll
        for (int k = 1; k < SB; ++k) {
            float4 v = ls[k][j];
            b.x += v.x; b.y += v.y; b.z += v.z; b.w += v.w;
        }
        wsBS4[((long long)c * nsb + sb) * 32 + j] = b;
    }
}

__global__ __launch_bounds__(512) void composite_kernel(
    const float* __restrict__ density,
    const float* __restrict__ feature,
    const float* __restrict__ depth,
    const float* __restrict__ wsA,
    const float* __restrict__ wsBS,
    float* __restrict__ wsB,    // [c][sb][512] partials
    int G, int nsb, int chunk)
{
    __shared__ float part[4][P];
    __shared__ float base[P];
    __shared__ float seg[SB][P];
    __shared__ float red[SB][512];
    const int tid = threadIdx.x;
    const int w = tid >> 6, t = tid & 63;
    const int sb = blockIdx.x, c = blockIdx.y;

    // base[p] = sum_{sb'<sb} wsBS[c][sb'][p], fixed-order 4-way split.
    {
        const int p = tid & (P - 1), j = tid >> 7;        // j = 0..3
        float s = 0.f;
        for (int sbp = j; sbp < sb; sbp += 4)
            s += wsBS[((long long)c * nsb + sbp) * P + p];
        part[j][p] = s;
    }
    // Own 8 segment sums -> LDS (2 coalesced loads per thread).
    {
        int idx = tid;
        int w2 = idx >> 7, p2 = idx & (P - 1);
        seg[w2][p2] = wsA[((long long)c * G + sb * SB + w2) * P + p2];
        idx += 512; w2 = idx >> 7; p2 = idx & (P - 1);
        seg[w2][p2] = wsA[((long long)c * G + sb * SB + w2) * P + p2];
    }
    __syncthreads();
    if (tid < P)
        base[tid] = (part[0][tid] + part[1][tid]) + (part[2][tid] + part[3][tid]);
    __syncthreads();

    const int p0 = 2 * t;
    float Sx = base[p0], Sy = base[p0 + 1];
    for (int k = 0; k < w; ++k) { Sx += seg[k][p0]; Sy += seg[k][p0 + 1]; }

    float fa0 = 0.f, fa1 = 0.f, fa2 = 0.f;
    float fb0 = 0.f, fb1 = 0.f, fb2 = 0.f;
    float da = 0.f, db = 0.f;

    const bool dead = __all((Sx > SKIP_S) && (Sy > SKIP_S));
    if (!dead) {
        const int g = sb * SB + w;
        const long long row0 = (long long)c * chunk + (long long)g * LROWS;
        const float2* __restrict__ d2 = (const float2*)density;
        const float2* __restrict__ z2 = (const float2*)depth;
        const float2* __restrict__ f2 = (const float2*)feature;
        float tx = __expf(-Sx), ty = __expf(-Sy);  // T at segment start
        #pragma unroll
        for (int r = 0; r < LROWS; ++r) {
            const long long hh = (row0 + r) * (P / 2) + t;
            float2 d = d2[hh];
            float2 z = z2[hh];
            float zn = __shfl_down(z.x, 1);
            float sx = d.x * (z.y - z.x);
            float sy = d.y * ((t == 63) ? FARD : (zn - z.y));
            float ex = __expf(-sx), ey = __expf(-sy);
            float tnx = tx * ex, tny = ty * ey;   // running cumprod, as ref
            float wx = tx - tnx;                  // T_i * (1 - temp_i)
            float wy = ty - tny;
            tx = tnx; ty = tny;
            const long long fi = 3 * hh;
            float2 f01 = f2[fi], f23 = f2[fi + 1], f45 = f2[fi + 2];
            fa0 += wx * f01.x; fa1 += wx * f01.y; fa2 += wx * f23.x;
            fb0 += wy * f23.y; fb1 += wy * f45.x; fb2 += wy * f45.y;
            da  += wx * z.x;   db  += wy * z.y;
        }
    }

    // Per-wave partials -> LDS. Layout per wave: [p*3+comp | 384+p].
    float* rw = red[w];
    rw[p0 * 3 + 0] = fa0; rw[p0 * 3 + 1] = fa1; rw[p0 * 3 + 2] = fa2;
    rw[p0 * 3 + 3] = fb0; rw[p0 * 3 + 4] = fb1; rw[p0 * 3 + 5] = fb2;
    rw[384 + p0] = da;    rw[384 + p0 + 1] = db;
    __syncthreads();

    float s = 0.f;
    #pragma unroll
    for (int k = 0; k < SB; ++k) s += red[k][tid];
    wsB[((long long)c * nsb + sb) * 512 + tid] = s;
}

__global__ __launch_bounds__(64) void reduce_kernel(
    const float* __restrict__ wsB,
    float* __restrict__ out,
    int nsb, int n_chunks)
{
    const int b = blockIdx.x;                     // 8 blocks per chunk
    const int c = b >> 3, q = b & 7;
    const int e = q * 64 + threadIdx.x;           // 0..511
    float s = 0.f;
    #pragma unroll 4
    for (int sb = 0; sb < nsb; ++sb)
        s += wsB[((long long)c * nsb + sb) * 512 + e];
    if (e < 384) out[(long long)c * 384 + e] = s;                    // feat
    else out[(long long)n_chunks * 384 + (long long)c * P + (e - 384)] = s;
}

extern "C" void kernel_launch(void* const* d_in, const int* in_sizes, int n_in,
                              void* d_out, int out_size, void* d_ws, size_t ws_size,
                              hipStream_t stream)
{
    const float* density = (const float*)d_in[0];
    const float* feature = (const float*)d_in[1];
    const float* depth   = (const float*)d_in[2];
    float* out = (float*)d_out;

    const int B = in_sizes[0] / P;        // 65536
    const int chunk = 8192;               // matches setup_inputs() chunk_size
    const int n_chunks = B / chunk;       // 8
    const int nsb = chunk / (SB * LROWS); // 128 superblocks per chunk
    const int G = nsb * SB;               // 1024 segments per chunk

    float* wsA  = (float*)d_ws;                          // 4 MB
    float* wsBS = wsA + (size_t)n_chunks * G * P;        // 0.5 MB
    float* wsB  = wsBS + (size_t)n_chunks * nsb * P;     // 2 MB

    dim3 grid(nsb, n_chunks);
    seg_sum_kernel<<<grid, 512, 0, stream>>>(
        (const float4*)density, (const float4*)depth,
        (float4*)wsA, (float4*)wsBS, G, nsb, chunk);
    composite_kernel<<<grid, 512, 0, stream>>>(
        density, feature, depth, wsA, wsBS, wsB, G, nsb, chunk);
    reduce_kernel<<<n_chunks * 8, 64, 0, stream>>>(wsB, out, nsb, n_chunks);
}